// Round 11
// baseline (18688.576 us; speedup 1.0000x reference)
//
#include <hip/hip_runtime.h>

#define HSZ 1024
#define TSTEPS 4096
#define NBLK 256
#define NTHR 256   // 4 waves/block x 256 blocks = 1024 waves == HSZ units
#define HV (HSZ / 4)
#define REP_BYTES 24576  // one replica: [2 parity][3 array][1024 tagged dwords]

typedef _Float16 half2v __attribute__((ext_vector_type(2)));

#if __has_builtin(__builtin_amdgcn_fdot2)
#define FDOT2(a, b, c) __builtin_amdgcn_fdot2((a), (b), (c), false)
#else
__device__ __forceinline__ float FDOT2(half2v a, half2v b, float c) {
    return c + (float)a.x * (float)b.x + (float)a.y * (float)b.y;
}
#endif

__device__ __forceinline__ float wave_reduce(float v) {
#pragma unroll
    for (int off = 32; off; off >>= 1) v += __shfl_xor(v, off, 64);
    return v;
}

__device__ __forceinline__ float sigm(float x) { return 1.0f / (1.0f + __expf(-x)); }

// ---- agent-coherent (L3-level) accesses, no cache fences ----
__device__ __forceinline__ unsigned long long ld_coh64(const unsigned long long* p) {
    return __hip_atomic_load(p, __ATOMIC_RELAXED, __HIP_MEMORY_SCOPE_AGENT);
}
__device__ __forceinline__ void st_coh32(unsigned* p, unsigned v) {
    __hip_atomic_store(p, v, __ATOMIC_RELAXED, __HIP_MEMORY_SCOPE_AGENT);
}

// Publish via return-less global_atomic_swap: executed AT the memory-side/L3
// atomic unit -> new value visible to remote sc1 loads at atomic-execute time,
// skipping the partial-line write-through/merge path of a plain sc1 store.
// No sc0 flag => no return value => fire-and-forget.
__device__ __forceinline__ void at_swap_nr(unsigned* p, unsigned v) {
    asm volatile("global_atomic_swap %0, %1, off"
                 :: "v"((unsigned long long)(uintptr_t)p), "v"(v)
                 : "memory");
}

__device__ __forceinline__ unsigned f16bits(float v) {
    _Float16 h = (_Float16)v;
    unsigned short b;
    __builtin_memcpy(&b, &h, 2);
    return (unsigned)b;
}

// Pin packed-f16 weight into a VGPR (prevents load re-sinking).
#define PINH(h) asm volatile("" : "+v"(h))

// f32->half2 (init path, RNE per element)
__device__ __forceinline__ half2v cvt2(float a, float b) {
    half2v r; r.x = (_Float16)a; r.y = (_Float16)b; return r;
}

// ---- split-phase poll: issue loads early, check late (flight hides under
// compute of the preceding layer). Retry loop only on stale first attempt. ----
struct PollQ { unsigned long long q0, q1; };

__device__ __forceinline__ PollQ poll_issue(const unsigned long long* Tq, int tid) {
    PollQ p;
    p.q0 = ld_coh64(Tq + tid);
    p.q1 = ld_coh64(Tq + 256 + tid);
    return p;
}

__device__ __forceinline__ void poll_complete(PollQ p, const unsigned long long* Tq,
                                              unsigned e, int tid, unsigned* lds32) {
    for (;;) {
        const bool ok0 = ((((unsigned)p.q0) >> 16) == e) && (((unsigned)(p.q0 >> 48)) == e);
        const bool ok1 = ((((unsigned)p.q1) >> 16) == e) && (((unsigned)(p.q1 >> 48)) == e);
        if (ok0 && ok1) break;
        __builtin_amdgcn_s_sleep(1);
        p.q0 = ld_coh64(Tq + tid);
        p.q1 = ld_coh64(Tq + 256 + tid);
    }
    lds32[tid]       = (((unsigned)(p.q0 >> 32)) << 16) | ((unsigned)p.q0 & 0xFFFFu);
    lds32[tid + 256] = (((unsigned)(p.q1 >> 32)) << 16) | ((unsigned)p.q1 & 0xFFFFu);
}

__global__ void __launch_bounds__(NTHR, 1) lstm_persist(
    const float* __restrict__ x,
    const float* __restrict__ Wih0, const float* __restrict__ Whh0,
    const float* __restrict__ bih0, const float* __restrict__ bhh0,
    const float* __restrict__ Wih12, const float* __restrict__ Whh12,
    const float* __restrict__ bih12, const float* __restrict__ bhh12,
    const float* __restrict__ Wres, const float* __restrict__ bres,
    float* __restrict__ out, float* __restrict__ ws_f, int nrep)
{
    char* wsb = (char*)ws_f;
    const int lane = threadIdx.x & 63;
    const int u = blockIdx.x * (NTHR / 64) + (threadIdx.x >> 6);  // hidden unit
    const int tid = threadIdx.x;

    __shared__ unsigned long long lds_h[3][256];  // 3 x 1024 f16

    // ---- init: parity 1 of every replica = tag 0, value 0 ----
    {
        const int gid = blockIdx.x * NTHR + tid;
        if (gid < nrep * 3072) {
            const int rep = gid / 3072, d = gid % 3072;
            st_coh32((unsigned*)(wsb + rep * REP_BYTES) + 3072 + d, 0u);
        }
    }

    // ---- per-wave scalar constants ----
    float b0[4], b1[4], b2[4], wx0a[4], wx0b[4];
#pragma unroll
    for (int g = 0; g < 4; ++g) {
        const int r = g * HSZ + u;
        b0[g] = bih0[r] + bhh0[r];
        b1[g] = bih12[r] + bhh12[r];
        b2[g] = bih12[4 * HSZ + r] + bhh12[4 * HSZ + r];
        wx0a[g] = Wih0[2 * r];
        wx0b[g] = Wih0[2 * r + 1];
    }

    // ---- register-resident f16 weights: 20 rows x 1024 -> 160 half2/lane ----
    const float4* Whh0v = (const float4*)Whh0;
    const float4* Wih1v = (const float4*)Wih12;
    const float4* Whh1v = (const float4*)Whh12;
    const float4* Wih2v = (const float4*)(Wih12 + 4 * HSZ * HSZ);
    const float4* Whh2v = (const float4*)(Whh12 + 4 * HSZ * HSZ);

    half2v w0h[4][8], wi1h[4][8], wh1h[4][8], wi2h[4][8], wh2h[4][8];
#pragma unroll
    for (int g = 0; g < 4; ++g) {
        const size_t r = (size_t)(g * HSZ + u) * HV + lane;
#pragma unroll
        for (int i = 0; i < 4; ++i) {
            float4 t;
            t = Whh0v[r + 64 * i];  w0h[g][2*i] = cvt2(t.x,t.y);  w0h[g][2*i+1] = cvt2(t.z,t.w);
            t = Wih1v[r + 64 * i];  wi1h[g][2*i] = cvt2(t.x,t.y); wi1h[g][2*i+1] = cvt2(t.z,t.w);
            t = Whh1v[r + 64 * i];  wh1h[g][2*i] = cvt2(t.x,t.y); wh1h[g][2*i+1] = cvt2(t.z,t.w);
            t = Wih2v[r + 64 * i];  wi2h[g][2*i] = cvt2(t.x,t.y); wi2h[g][2*i+1] = cvt2(t.z,t.w);
            t = Whh2v[r + 64 * i];  wh2h[g][2*i] = cvt2(t.x,t.y); wh2h[g][2*i+1] = cvt2(t.z,t.w);
        }
    }
#pragma unroll
    for (int g = 0; g < 4; ++g)
#pragma unroll
        for (int j = 0; j < 8; ++j) {
            PINH(w0h[g][j]); PINH(wi1h[g][j]); PINH(wh1h[g][j]);
            PINH(wi2h[g][j]); PINH(wh2h[g][j]);
        }

    // head weights as f16 (used only by wave u==0)
    half2v wresh[8];
    {
        const float4* wr = (const float4*)Wres;
#pragma unroll
        for (int i = 0; i < 4; ++i) {
            float4 t = wr[lane + 64 * i];
            wresh[2*i] = cvt2(t.x, t.y); wresh[2*i+1] = cvt2(t.z, t.w);
        }
    }
    const float bres0 = bres[0];

    // Drain init stores so no late init write can clobber a live tagged word.
    asm volatile("s_waitcnt vmcnt(0)" ::: "memory");
    __syncthreads();

    const unsigned long long* Tmyq =
        (const unsigned long long*)(wsb + (blockIdx.x % nrep) * REP_BYTES);

    float c0 = 0.0f, c1 = 0.0f, c2 = 0.0f;
    union Q { unsigned long long q; half2v h[2]; };

    // Wavefront pipeline, split-phase polls + atomic publish:
    //   iter k: [pq0 prefetched last iter] check0 -> issue pq1 -> L0 -> pub h0
    //           -> check1 -> issue pq2 -> L1 -> pub h1
    //           -> check2 -> issue pq0(next parity) -> head,L2 -> pub h2
    PollQ pq0 = poll_issue(Tmyq + 1536, tid);  // k=0 reads parity 1, array 0

    for (int k = 0; k <= TSTEPS + 2; ++k) {
        const int wp = k & 1, rp = wp ^ 1;
        const unsigned e = (unsigned)k;
        const unsigned long long* Trp = Tmyq + rp * 1536;
        const unsigned long long* Tnx = Tmyq + wp * 1536;  // next iter's read parity
        const bool pub = (k <= TSTEPS + 1);
        const unsigned tg = (unsigned)(k + 1) << 16;

        // ================= layer 0 =================
        poll_complete(pq0, Trp, e, tid, (unsigned*)lds_h[0]);
        PollQ pq1 = poll_issue(Trp + 512, tid);  // in flight during L0
        __syncthreads();

        half2v haf[8];
#pragma unroll
        for (int i = 0; i < 4; ++i) {
            Q q; q.q = lds_h[0][lane + 64 * i];
            haf[2*i] = q.h[0]; haf[2*i+1] = q.h[1];
        }

        float h0v = 0.0f;
        if (k < TSTEPS) {
            const float x0 = x[2 * k], x1 = x[2 * k + 1];
            float acc[4];
#pragma unroll
            for (int g = 0; g < 4; ++g) {
                float a = 0.0f;
#pragma unroll
                for (int j = 0; j < 8; ++j) a = FDOT2(w0h[g][j], haf[j], a);
                acc[g] = a;
            }
#pragma unroll
            for (int g = 0; g < 4; ++g)
                acc[g] = wave_reduce(acc[g]) + b0[g] + wx0a[g] * x0 + wx0b[g] * x1;
            const float ig = sigm(acc[0]), fg = sigm(acc[1]);
            const float gg = tanhf(acc[2]), og = sigm(acc[3]);
            c0 = fg * c0 + ig * gg;
            h0v = og * tanhf(c0);
        }
        if (lane == 0 && pub) {
            const unsigned wb = tg | f16bits(h0v);
            for (int rep = 0; rep < nrep; ++rep)
                at_swap_nr((unsigned*)(wsb + rep * REP_BYTES) + wp * 3072 + u, wb);
        }

        // ================= layer 1 =================
        poll_complete(pq1, Trp + 512, e, tid, (unsigned*)lds_h[1]);
        PollQ pq2 = poll_issue(Trp + 1024, tid);  // in flight during L1
        __syncthreads();

        half2v hbf[8];
#pragma unroll
        for (int i = 0; i < 4; ++i) {
            Q q; q.q = lds_h[1][lane + 64 * i];
            hbf[2*i] = q.h[0]; hbf[2*i+1] = q.h[1];
        }

        float h1v = 0.0f;
        if (k >= 1 && k <= TSTEPS) {
            float acc[4];
#pragma unroll
            for (int g = 0; g < 4; ++g) {
                float a = 0.0f;
#pragma unroll
                for (int j = 0; j < 8; ++j) {
                    a = FDOT2(wi1h[g][j], haf[j], a);
                    a = FDOT2(wh1h[g][j], hbf[j], a);
                }
                acc[g] = a;
            }
#pragma unroll
            for (int g = 0; g < 4; ++g) acc[g] = wave_reduce(acc[g]) + b1[g];
            const float ig = sigm(acc[0]), fg = sigm(acc[1]);
            const float gg = tanhf(acc[2]), og = sigm(acc[3]);
            c1 = fg * c1 + ig * gg;
            h1v = og * tanhf(c1);
        }
        if (lane == 0 && pub) {
            const unsigned wb = tg | f16bits(h1v);
            for (int rep = 0; rep < nrep; ++rep)
                at_swap_nr((unsigned*)(wsb + rep * REP_BYTES) + wp * 3072 + 1024 + u, wb);
        }

        // ================= layer 2 + head =================
        poll_complete(pq2, Trp + 1024, e, tid, (unsigned*)lds_h[2]);
        pq0 = poll_issue(Tnx, tid);  // next iter's array 0, in flight during L2
        __syncthreads();

        half2v hcf[8];
#pragma unroll
        for (int i = 0; i < 4; ++i) {
            Q q; q.q = lds_h[2][lane + 64 * i];
            hcf[2*i] = q.h[0]; hcf[2*i+1] = q.h[1];
        }

        if (u == 0 && k >= 3) {
            float a = 0.0f;
#pragma unroll
            for (int j = 0; j < 8; ++j) a = FDOT2(wresh[j], hcf[j], a);
            a = wave_reduce(a) + bres0;
            if (lane == 0) out[k - 3] = sigm(a);
        }

        float h2v = 0.0f;
        if (k >= 2 && k <= TSTEPS + 1) {
            float acc[4];
#pragma unroll
            for (int g = 0; g < 4; ++g) {
                float a = 0.0f;
#pragma unroll
                for (int j = 0; j < 8; ++j) {
                    a = FDOT2(wi2h[g][j], hbf[j], a);
                    a = FDOT2(wh2h[g][j], hcf[j], a);
                }
                acc[g] = a;
            }
#pragma unroll
            for (int g = 0; g < 4; ++g) acc[g] = wave_reduce(acc[g]) + b2[g];
            const float ig = sigm(acc[0]), fg = sigm(acc[1]);
            const float gg = tanhf(acc[2]), og = sigm(acc[3]);
            c2 = fg * c2 + ig * gg;
            h2v = og * tanhf(c2);
        }
        if (lane == 0 && pub) {
            const unsigned wb = tg | f16bits(h2v);
            for (int rep = 0; rep < nrep; ++rep)
                at_swap_nr((unsigned*)(wsb + rep * REP_BYTES) + wp * 3072 + 2048 + u, wb);
        }
    }
}

extern "C" void kernel_launch(void* const* d_in, const int* in_sizes, int n_in,
                              void* d_out, int out_size, void* d_ws, size_t ws_size,
                              hipStream_t stream) {
    const float* x     = (const float*)d_in[0];
    const float* Wih0  = (const float*)d_in[1];
    const float* Whh0  = (const float*)d_in[2];
    const float* bih0  = (const float*)d_in[3];
    const float* bhh0  = (const float*)d_in[4];
    const float* Wih12 = (const float*)d_in[5];
    const float* Whh12 = (const float*)d_in[6];
    const float* bih12 = (const float*)d_in[7];
    const float* bhh12 = (const float*)d_in[8];
    const float* Wres  = (const float*)d_in[9];
    const float* bres  = (const float*)d_in[10];
    float* out = (float*)d_out;
    float* ws  = (float*)d_ws;

    int nrep = (int)(ws_size / REP_BYTES);
    if (nrep > 8) nrep = 8;
    if (nrep < 1) nrep = 1;

    lstm_persist<<<dim3(NBLK), dim3(NTHR), 0, stream>>>(
        x, Wih0, Whh0, bih0, bhh0, Wih12, Whh12, bih12, bhh12,
        Wres, bres, out, ws, nrep);
}